// Round 2
// baseline (1033.433 us; speedup 1.0000x reference)
//
#include <hip/hip_runtime.h>
#include <hip/hip_bf16.h>

typedef __attribute__((ext_vector_type(8))) short bf16x8;
typedef __attribute__((ext_vector_type(4))) float f32x4;
typedef unsigned short u16;

#define MFMA16(a, b, c) __builtin_amdgcn_mfma_f32_16x16x32_bf16((a), (b), (c), 0, 0, 0)

__device__ __forceinline__ u16 f2b(float f) {
  union { float f; unsigned u; } x; x.f = f;
  return (u16)((x.u + 0x7FFFu + ((x.u >> 16) & 1u)) >> 16);  // RNE
}

// ---------------- x fp32 -> bf16 ----------------
__global__ __launch_bounds__(256) void k_cvt(const float* __restrict__ in,
                                             u16* __restrict__ out, int n4) {
  int i = blockIdx.x * 256 + threadIdx.x;
  if (i >= n4) return;
  float4 v = ((const float4*)in)[i];
  u16 a = f2b(v.x), b = f2b(v.y), c = f2b(v.z), d = f2b(v.w);
  ((uint2*)out)[i] = make_uint2((unsigned)a | ((unsigned)b << 16),
                                (unsigned)c | ((unsigned)d << 16));
}

// ---------------- transpose+convert: out[C][R] = bf16(in[R][C]) ----------------
__global__ __launch_bounds__(256) void k_packT(const float* __restrict__ in,
                                               u16* __restrict__ out, int R, int C) {
  __shared__ float t[32][33];
  int r0 = blockIdx.x * 32, c0 = blockIdx.y * 32;
  int cx = threadIdx.x & 31, ry = threadIdx.x >> 5;
#pragma unroll
  for (int k = 0; k < 4; k++)
    t[ry + k * 8][cx] = in[(size_t)(r0 + ry + k * 8) * C + c0 + cx];
  __syncthreads();
#pragma unroll
  for (int k = 0; k < 4; k++)
    out[(size_t)(c0 + ry + k * 8) * R + r0 + cx] = f2b(t[cx][ry + k * 8]);
}

// ---------------- q,k projection: [16384][64] each, q pre-scaled by 1/8 ----------------
__global__ __launch_bounds__(256) void k_gemm_qk(const u16* __restrict__ xb,
                                                 const u16* __restrict__ wqt,
                                                 const u16* __restrict__ wkt,
                                                 u16* __restrict__ q, u16* __restrict__ kk) {
  int row0 = blockIdx.x * 64;
  int tid = threadIdx.x, w = tid >> 6, l = tid & 63, l15 = l & 15, lg = l >> 4;
  const u16* wt = (w < 2) ? wqt : wkt;
  int nbase = (w & 1) * 32;
  f32x4 acc[4][2];
#pragma unroll
  for (int mt = 0; mt < 4; mt++)
#pragma unroll
    for (int nt = 0; nt < 2; nt++) acc[mt][nt] = (f32x4){0.f, 0.f, 0.f, 0.f};

  for (int k0 = 0; k0 < 1024; k0 += 32) {
    bf16x8 bfr[2], afr[4];
#pragma unroll
    for (int nt = 0; nt < 2; nt++)
      bfr[nt] = *(const bf16x8*)&wt[(size_t)(nbase + nt * 16 + l15) * 1024 + k0 + lg * 8];
#pragma unroll
    for (int mt = 0; mt < 4; mt++)
      afr[mt] = *(const bf16x8*)&xb[(size_t)(row0 + mt * 16 + l15) * 1024 + k0 + lg * 8];
#pragma unroll
    for (int mt = 0; mt < 4; mt++)
#pragma unroll
      for (int nt = 0; nt < 2; nt++) acc[mt][nt] = MFMA16(afr[mt], bfr[nt], acc[mt][nt]);
  }
  float scale = (w < 2) ? 0.125f : 1.0f;  // fold head_size^-0.5 into q
  u16* dst = (w < 2) ? q : kk;
#pragma unroll
  for (int mt = 0; mt < 4; mt++)
#pragma unroll
    for (int nt = 0; nt < 2; nt++)
#pragma unroll
      for (int j = 0; j < 4; j++)
        dst[(size_t)(row0 + mt * 16 + lg * 4 + j) * 64 + nbase + nt * 16 + l15] =
            f2b(acc[mt][nt][j] * scale);
}

// ---------------- v projection, transposed: vT[b][d][s] ----------------
__global__ __launch_bounds__(256) void k_gemm_v(const u16* __restrict__ xb,
                                                const u16* __restrict__ wvt,
                                                u16* __restrict__ vT) {
  int b = blockIdx.z;
  int m0 = blockIdx.y * 128;  // d_out
  int n0 = blockIdx.x * 128;  // s
  int tid = threadIdx.x, w = tid >> 6, l = tid & 63, l15 = l & 15, lg = l >> 4;
  int nb = n0 + w * 32;
  const u16* xrow = xb + (size_t)(b * 4096 + nb) * 1024;
  f32x4 acc[8][2];
#pragma unroll
  for (int mt = 0; mt < 8; mt++)
#pragma unroll
    for (int nt = 0; nt < 2; nt++) acc[mt][nt] = (f32x4){0.f, 0.f, 0.f, 0.f};

  for (int k0 = 0; k0 < 1024; k0 += 32) {
    bf16x8 bfr[2], afr[8];
#pragma unroll
    for (int nt = 0; nt < 2; nt++)
      bfr[nt] = *(const bf16x8*)&xrow[(size_t)(nt * 16 + l15) * 1024 + k0 + lg * 8];
#pragma unroll
    for (int mt = 0; mt < 8; mt++)
      afr[mt] = *(const bf16x8*)&wvt[(size_t)(m0 + mt * 16 + l15) * 1024 + k0 + lg * 8];
#pragma unroll
    for (int mt = 0; mt < 8; mt++)
#pragma unroll
      for (int nt = 0; nt < 2; nt++) acc[mt][nt] = MFMA16(afr[mt], bfr[nt], acc[mt][nt]);
  }
#pragma unroll
  for (int mt = 0; mt < 8; mt++)
#pragma unroll
    for (int nt = 0; nt < 2; nt++)
#pragma unroll
      for (int j = 0; j < 4; j++)
        vT[((size_t)b * 1024 + m0 + mt * 16 + lg * 4 + j) * 4096 + nb + nt * 16 + l15] =
            f2b(acc[mt][nt][j]);
}

// ---------------- barrier-free flash attention ----------------
// Block: 8 independent waves. Wave owns 32 q-rows x 128 d-cols of O^T.
// Per KV-tile(64): QK (16 MFMA) -> wave-local softmax (shfl over 16-lane col
// group) -> P via wave-private swizzled LDS -> PV (32 MFMA) + l via ones-MFMA.
__global__ __launch_bounds__(512, 2) void k_attn(const u16* __restrict__ qw,
                                                 const u16* __restrict__ kw,
                                                 const u16* __restrict__ vT,
                                                 float* __restrict__ out) {
  int qtile = 15 - blockIdx.x;  // long blocks dispatch first
  int chunk = blockIdx.y, b = blockIdx.z;
  int tid = threadIdx.x, w = tid >> 6, l = tid & 63, l15 = l & 15, lg = l >> 4;
  int qbase = qtile * 256 + w * 32;
  int d0 = chunk * 128;
  size_t tokb = (size_t)b * 4096;

  __shared__ __align__(16) u16 P_all[8 * 2048];  // 4KB per wave, XOR-swizzled
  char* Pb = (char*)&P_all[w * 2048];

  bf16x8 qf[2][2];
#pragma unroll
  for (int qt = 0; qt < 2; qt++)
#pragma unroll
    for (int ks = 0; ks < 2; ks++)
      qf[qt][ks] = *(const bf16x8*)&qw[(tokb + qbase + qt * 16 + l15) * 64 + ks * 32 + lg * 8];

  f32x4 acc[8][2];   // [d-tile][q-subtile]
  f32x4 accl[2];     // running row-sum l (via ones-row MFMA), cols = q
  float mrow[2][4];  // running max, QK layout rows lg*4+j
#pragma unroll
  for (int mt = 0; mt < 8; mt++)
#pragma unroll
    for (int qt = 0; qt < 2; qt++) acc[mt][qt] = (f32x4){0.f, 0.f, 0.f, 0.f};
#pragma unroll
  for (int qt = 0; qt < 2; qt++) {
    accl[qt] = (f32x4){0.f, 0.f, 0.f, 0.f};
#pragma unroll
    for (int j = 0; j < 4; j++) mrow[qt][j] = -1e30f;
  }
  const short ob = (short)0x3F80;  // bf16 1.0
  const bf16x8 ones = {ob, ob, ob, ob, ob, ob, ob, ob};
  const size_t vbase = (size_t)b * 1024 + d0;

  int ntiles = ((qbase + 31) >> 6) + 1;
  for (int t = 0; t < ntiles; t++) {
    int s0 = t * 64;
    // ---- QK^T ----
    f32x4 sfr[2][4];
#pragma unroll
    for (int nt = 0; nt < 4; nt++) {
      const u16* kr = &kw[(tokb + s0 + nt * 16 + l15) * 64 + lg * 8];
      bf16x8 kf0 = *(const bf16x8*)kr;
      bf16x8 kf1 = *(const bf16x8*)(kr + 32);
#pragma unroll
      for (int qt = 0; qt < 2; qt++) {
        f32x4 z = (f32x4){0.f, 0.f, 0.f, 0.f};
        z = MFMA16(qf[qt][0], kf0, z);
        sfr[qt][nt] = MFMA16(qf[qt][1], kf1, z);
      }
    }
    if (t == ntiles - 1) {  // causal mask, final tile only
#pragma unroll
      for (int qt = 0; qt < 2; qt++)
#pragma unroll
        for (int nt = 0; nt < 4; nt++) {
          int sg = s0 + nt * 16 + l15;
#pragma unroll
          for (int j = 0; j < 4; j++)
            if (sg > qbase + qt * 16 + lg * 4 + j) sfr[qt][nt][j] = -1e30f;
        }
    }
    // ---- wave-local row max (reduce over 16-lane col group) ----
    float pmax[2][4];
    int need = 0;
#pragma unroll
    for (int qt = 0; qt < 2; qt++) {
#pragma unroll
      for (int j = 0; j < 4; j++)
        pmax[qt][j] = fmaxf(fmaxf(sfr[qt][0][j], sfr[qt][1][j]),
                            fmaxf(sfr[qt][2][j], sfr[qt][3][j]));
#pragma unroll
      for (int msk = 1; msk <= 8; msk <<= 1)
#pragma unroll
        for (int j = 0; j < 4; j++)
          pmax[qt][j] = fmaxf(pmax[qt][j], __shfl_xor(pmax[qt][j], msk));
#pragma unroll
      for (int j = 0; j < 4; j++) need |= (pmax[qt][j] > mrow[qt][j] + 8.0f);
    }
    if (__any(need)) {  // T13 defer-max: rescale only on real max growth
      float scq[2];
#pragma unroll
      for (int qt = 0; qt < 2; qt++) {
        float sc[4];
#pragma unroll
        for (int j = 0; j < 4; j++) {
          float mn = fmaxf(mrow[qt][j], pmax[qt][j]);
          sc[j] = __expf(mrow[qt][j] - mn);
          mrow[qt][j] = mn;
        }
        float s = 1.f;
#pragma unroll
        for (int j = 0; j < 4; j++) {  // transpose row-scale -> col-scale
          float tv = __shfl(sc[j], (l15 >> 2) * 16);
          if ((l15 & 3) == j) s = tv;
        }
        scq[qt] = s;
      }
#pragma unroll
      for (int mt = 0; mt < 8; mt++)
#pragma unroll
        for (int qt = 0; qt < 2; qt++) acc[mt][qt] *= scq[qt];
      accl[0] *= scq[0];
      accl[1] *= scq[1];
    }
    // ---- P = exp(S - m) -> swizzled wave-private LDS ----
#pragma unroll
    for (int qt = 0; qt < 2; qt++)
#pragma unroll
      for (int nt = 0; nt < 4; nt++)
#pragma unroll
        for (int j = 0; j < 4; j++) {
          int R = qt * 16 + lg * 4 + j;
          float p = __expf(sfr[qt][nt][j] - mrow[qt][j]);
          int addr = (R * 128 + (nt * 16 + l15) * 2) ^ ((R & 7) << 4);
          *(u16*)(Pb + addr) = f2b(p);
        }
    asm volatile("" ::: "memory");  // keep compile-time order; HW LDS is in-order per wave
    // ---- read P^T fragments ----
    bf16x8 pf[2][2];
#pragma unroll
    for (int qt = 0; qt < 2; qt++)
#pragma unroll
      for (int ks = 0; ks < 2; ks++) {
        int R = qt * 16 + l15;
        int addr = (R * 128 + ks * 64 + lg * 16) ^ ((R & 7) << 4);
        pf[qt][ks] = *(const bf16x8*)(Pb + addr);
      }
    // ---- l += colsum(P) via ones-row MFMA ----
#pragma unroll
    for (int qt = 0; qt < 2; qt++) {
      accl[qt] = MFMA16(ones, pf[qt][0], accl[qt]);
      accl[qt] = MFMA16(ones, pf[qt][1], accl[qt]);
    }
    // ---- O^T += V^T P^T ----
#pragma unroll
    for (int mt = 0; mt < 8; mt++) {
      const u16* vr = &vT[(vbase + mt * 16 + l15) * 4096 + s0 + lg * 8];
      bf16x8 va0 = *(const bf16x8*)vr;
      bf16x8 va1 = *(const bf16x8*)(vr + 32);
#pragma unroll
      for (int qt = 0; qt < 2; qt++) {
        acc[mt][qt] = MFMA16(va0, pf[qt][0], acc[mt][qt]);
        acc[mt][qt] = MFMA16(va1, pf[qt][1], acc[mt][qt]);
      }
    }
  }
  // ---- epilogue: divide by l, store O ----
#pragma unroll
  for (int qt = 0; qt < 2; qt++) {
    float linv = 1.0f / accl[qt][0];
#pragma unroll
    for (int mt = 0; mt < 8; mt++) {
      f32x4 v = acc[mt][qt] * linv;
      size_t o = (tokb + qbase + qt * 16 + l15) * 1024 + d0 + mt * 16 + lg * 4;
      *(f32x4*)&out[o] = v;
    }
  }
}

// ---------------- launch ----------------
extern "C" void kernel_launch(void* const* d_in, const int* in_sizes, int n_in,
                              void* d_out, int out_size, void* d_ws, size_t ws_size,
                              hipStream_t stream) {
  const float* x  = (const float*)d_in[0];
  const float* Wq = (const float*)d_in[1];
  const float* Wk = (const float*)d_in[2];
  const float* Wv = (const float*)d_in[3];
  float* out = (float*)d_out;
  char* ws = (char*)d_ws;
  u16* xb  = (u16*)(ws);              // 16384x1024 bf16
  u16* qw  = (u16*)(ws + 33554432);   // 16384x64
  u16* kw  = (u16*)(ws + 35651584);   // 16384x64
  u16* vT  = (u16*)(ws + 37748736);   // 4x1024x4096
  u16* wqt = (u16*)(ws + 71303168);   // 64x1024
  u16* wkt = (u16*)(ws + 71434240);   // 64x1024
  u16* wvt = (u16*)(ws + 71565312);   // 1024x1024

  k_cvt<<<16384, 256, 0, stream>>>(x, xb, 4194304);
  k_packT<<<dim3(32, 2), 256, 0, stream>>>(Wq, wqt, 1024, 64);
  k_packT<<<dim3(32, 2), 256, 0, stream>>>(Wk, wkt, 1024, 64);
  k_packT<<<dim3(32, 32), 256, 0, stream>>>(Wv, wvt, 1024, 1024);
  k_gemm_qk<<<256, 256, 0, stream>>>(xb, wqt, wkt, qw, kw);
  k_gemm_v<<<dim3(32, 8, 4), 256, 0, stream>>>(xb, wvt, vT);
  k_attn<<<dim3(16, 8, 4), 512, 0, stream>>>(qw, kw, vT, out);
}